// Round 8
// baseline (8141.460 us; speedup 1.0000x reference)
//
#include <hip/hip_runtime.h>

// BiLSTMTagger on MI355X (gfx950) — 256 MB workspace budget.
// Chunked pipeline (16 chunks x 32 steps per layer):
//   gemm_gx(chunk): gathered-A GEMM -> gx chunk (bwd pre-gathered) + PROLOGUE
//                   poisons hseq with fp16-NaN 0x7FFF for the next scan.
//   lstm_scan(chunk): persistent 256-block scan, W_hh register/AGPR-resident.
//     Sync = POLL-ON-DATA: hseq has one write-once slot per step; producers
//     emit 16B sc1 stores (no waitcnt, no tag); consumers' A-fragment granules
//     are 1:1 with producer stores and are polled until all 8 halves != poison
//     (h = sig*tanh of finite values -> never NaN -> never 0x7FFF).
//     One LLC hop per step instead of ~5 (tag store + ack + poll + load gone).
//     Chunk-boundary h carried via hcarry (plain stores, kernel-boundary
//     coherence); AT s0==0 THE INITIAL h IS ZERO — do NOT read hcarry (r7 bug:
//     layer 2 chunk 0 read layer 1's final h).
//   layer2: scan emits step-indexed chunk buffer; classifier = two separable
//           K=512 partial GEMMs accumulating into bias-initialized d_out.
// fp16 storage/MFMA, fp32 cell math.

typedef unsigned short u16;
typedef unsigned long long u64;
typedef _Float16 f16;
typedef __attribute__((ext_vector_type(8))) _Float16 f16x8;
typedef __attribute__((ext_vector_type(4))) float f32x4;

#define TT 512
#define HH 512
#define CH 32          // steps per chunk
#define NCH 16         // chunks
#define POISON 0x7FFFu // fp16 NaN; f2h of finite never produces it

__device__ __forceinline__ u16 f2h(float f) { f16 h = (f16)f; return __builtin_bit_cast(u16, h); }
__device__ __forceinline__ float h2f(u16 s) { return (float)__builtin_bit_cast(f16, s); }
__device__ __forceinline__ float sigf(float x) { return 1.f / (1.f + __expf(-x)); }
__device__ __forceinline__ float tanhf_(float x) { return 1.f - 2.f / (__expf(2.f * x) + 1.f); }
__device__ __forceinline__ f32x4 zf4() { f32x4 z; z[0]=0.f; z[1]=0.f; z[2]=0.f; z[3]=0.f; return z; }

// agent-scope (sc1) 16B ops: bypass the non-coherent per-XCD L2, land in LLC
__device__ __forceinline__ void gstore16_sc1(u16* p, f16x8 v) {
  asm volatile("global_store_dwordx4 %0, %1, off sc1" :: "v"(p), "v"(v) : "memory");
}
__device__ __forceinline__ void gload16_sc1(f16x8& v, const u16* p) {
  asm volatile("global_load_dwordx4 %0, %1, off sc1" : "=v"(v) : "v"(p) : "memory");
}

// ---------------- utility kernels ----------------

struct CvtJob { const float* s; u16* d; int n; };
struct CvtJobs { CvtJob j[9]; };

__global__ void cvt_many(CvtJobs jobs) {
  CvtJob jb = jobs.j[blockIdx.y];
  int i = blockIdx.x * 256 + threadIdx.x;
  if (i < jb.n) jb.d[i] = f2h(jb.s[i]);
}

__global__ void embed_cast(const int* __restrict__ x, const float* __restrict__ emb,
                           u16* __restrict__ e) {
  int row = blockIdx.x;                 // b*T+t
  int tok = x[row];
  e[(size_t)row * 256 + threadIdx.x] = f2h(emb[(size_t)tok * 256 + threadIdx.x]);
}

__global__ void bias_init(float* __restrict__ o, const float* __restrict__ b, int n) {
  int i = blockIdx.x * 256 + threadIdx.x;
  if (i < n) o[i] = b[i & 63];
}

__global__ void fill_diag(float* __restrict__ o, int n, float sentinel) {
  int i = blockIdx.x * 256 + threadIdx.x;
  if (i < n) o[i] = (i == 0) ? sentinel : 0.f;
}

// ---------------- persistent BiLSTM scan, one chunk ----------------
// grid 256 x 128 thr (2 independent waves/block, no __syncthreads).
// Wave = one unit-tile: 16 batches x 16 units x 4 gates.
// hseq[dir][slot=0..CH-1][128][512]: h AFTER step s0+slot, write-once,
// pre-poisoned. Slot CH-1 unused (carry goes via hcarry, plain stores).
// Consumer at step i polls slot i-1; i==0 reads hcarry (s0>0) or zeros (s0==0).

__global__ __launch_bounds__(128, 1) void lstm_scan(
    const u16* __restrict__ gxc, const u16* __restrict__ whh_f,
    const u16* __restrict__ whh_b, const int* __restrict__ len,
    u16* __restrict__ out_pos, u16* __restrict__ out_chunk,
    u16* __restrict__ hseq, u16* __restrict__ hcarry,
    float* __restrict__ cbuf, int s0)
{
  __shared__ u16 tb[2][256];                 // 16x16 transpose tile per wave
  const int bi = blockIdx.x;
  const int dir = bi >> 7;
  const int sub = bi & 127;
  const int b_base = (sub >> 4) * 16;
  const int u_tile = (sub & 15) * 2 + (threadIdx.x >> 6);
  const int u_base = u_tile * 16;
  const int lane = threadIdx.x & 63;
  const int m16 = lane & 15, quad = lane >> 4;
  const u16* gxd = gxc + (size_t)dir * 4096 * 2048;
  const u16* whh = dir ? whh_b : whh_f;
  u16* T = tb[threadIdx.x >> 6];

  // W_hh fragments: B[n=lane&15][k=quad*8+j], rows g*512 + u_base + n.
  // 64 f16x8 = 256 regs -> AGPRs (gfx950 unified file).
  f16x8 bf[4][16];
#pragma unroll
  for (int g = 0; g < 4; ++g) {
    const u16* wrow = whh + (size_t)(g * HH + u_base + m16) * HH + quad * 8;
#pragma unroll
    for (int ks = 0; ks < 16; ++ks)
      bf[g][ks] = *(const f16x8*)(wrow + ks * 32);
  }

  int lenr[4];
#pragma unroll
  for (int r = 0; r < 4; ++r) lenr[r] = len[b_base + quad * 4 + r];

  float cst[4];
  if (s0 == 0) {
#pragma unroll
    for (int r = 0; r < 4; ++r) cst[r] = 0.f;
  } else {
#pragma unroll
    for (int r = 0; r < 4; ++r)
      cst[r] = cbuf[(size_t)dir * 65536 + (b_base + quad * 4 + r) * HH + u_base + m16];
  }

  const u16* carry_rd = hcarry + (size_t)dir * 65536 + (b_base + m16) * HH + quad * 8;

  for (int i = 0; i < CH; ++i) {
    const int s = s0 + i;

    // gx prefetch (latency hides under the poll)
    u16 gpre[4][4];
#pragma unroll
    for (int r = 0; r < 4; ++r) {
      const int batch = b_base + quad * 4 + r;
      const u16* gq = gxd + (size_t)(batch * CH + i) * 2048 + u_base + m16;
      gpre[r][0] = gq[0]; gpre[r][1] = gq[512];
      gpre[r][2] = gq[1024]; gpre[r][3] = gq[1536];
    }

    // A fragments = h[s-1]: poll-on-data (granules are the fragments)
    f16x8 a[16];
    if (i == 0) {
      if (s0 == 0) {
        // initial h = 0 (r7 BUG FIX: hcarry holds the PREVIOUS layer's final
        // h at layer entry — must not be read at s0==0)
#pragma unroll
        for (int ks = 0; ks < 16; ++ks)
#pragma unroll
          for (int j = 0; j < 8; ++j) a[ks][j] = (f16)0.f;
      } else {
#pragma unroll
        for (int ks = 0; ks < 16; ++ks)
          a[ks] = *(const f16x8*)(carry_rd + ks * 32);   // kernel-boundary coherent
      }
    } else {
      const u16* sb = hseq + ((size_t)(dir * CH + (i - 1)) * 128 + b_base + m16) * HH + quad * 8;
      while (true) {
#pragma unroll
        for (int ks = 0; ks < 16; ++ks) gload16_sc1(a[ks], sb + ks * 32);
        asm volatile("s_waitcnt vmcnt(0)" ::: "memory");
        bool ok = true;
#pragma unroll
        for (int ks = 0; ks < 16; ++ks) {
          union { f16x8 v; u16 w[8]; } u; u.v = a[ks];
#pragma unroll
          for (int j = 0; j < 8; ++j) ok &= (u.w[j] != POISON);
        }
        if (__ballot(!ok) == 0ull) break;
        __builtin_amdgcn_s_sleep(1);
      }
    }

    f32x4 a0 = zf4(), a1 = zf4(), a2 = zf4(), a3 = zf4();
#pragma unroll
    for (int ks = 0; ks < 16; ++ks) {
      a0 = __builtin_amdgcn_mfma_f32_16x16x32_f16(a[ks], bf[0][ks], a0, 0, 0, 0);
      a1 = __builtin_amdgcn_mfma_f32_16x16x32_f16(a[ks], bf[1][ks], a1, 0, 0, 0);
      a2 = __builtin_amdgcn_mfma_f32_16x16x32_f16(a[ks], bf[2][ks], a2, 0, 0, 0);
      a3 = __builtin_amdgcn_mfma_f32_16x16x32_f16(a[ks], bf[3][ks], a3, 0, 0, 0);
    }

    // cell math
    u16 hv[4];
#pragma unroll
    for (int r = 0; r < 4; ++r) {
      float gi = a0[r] + h2f(gpre[r][0]);
      float gf = a1[r] + h2f(gpre[r][1]);
      float gg = a2[r] + h2f(gpre[r][2]);
      float go = a3[r] + h2f(gpre[r][3]);
      float c = sigf(gf) * cst[r] + sigf(gi) * tanhf_(gg);
      cst[r] = c;
      hv[r] = f2h(sigf(go) * tanhf_(c));
    }

    // publish h: LDS 16x16 transpose -> 16B granule stores (sc1, NO waitcnt)
#pragma unroll
    for (int r = 0; r < 4; ++r)
      T[(quad * 4 + r) * 16 + m16] = hv[r];     // [batch_row][unit]
    if (lane < 32) {
      const int brow = lane >> 1, col8 = (lane & 1) * 8;
      f16x8 hrow = *(const f16x8*)&T[brow * 16 + col8];
      if (i == CH - 1) {
        *(f16x8*)(hcarry + (size_t)dir * 65536 + (b_base + brow) * HH + u_base + col8) = hrow;
      } else {
        u16* dst = hseq + ((size_t)(dir * CH + i) * 128 + b_base + brow) * HH + u_base + col8;
        gstore16_sc1(dst, hrow);
      }
    }

    // outputs (plain stores)
#pragma unroll
    for (int r = 0; r < 4; ++r) {
      const int batch = b_base + quad * 4 + r;
      const int L = lenr[r];
      const bool valid = s < L;
      if (out_pos) {
        const int p = dir ? (L - 1 - s) : s;
        const int wrow = valid ? (p < 0 ? 0 : p) : s;
        out_pos[(size_t)(batch * TT + wrow) * 1024 + dir * 512 + u_base + m16]
            = valid ? hv[r] : (u16)0;
      } else {
        out_chunk[(size_t)(batch * CH + i) * 1024 + dir * 512 + u_base + m16] = hv[r];
      }
    }
  }

#pragma unroll
  for (int r = 0; r < 4; ++r)
    cbuf[(size_t)dir * 65536 + (b_base + quad * 4 + r) * HH + u_base + m16] = cst[r];
}

// ---------------- gx GEMM (gathered A rows) + hseq poison prologue ----------------
// gxc[dir][m][n] = A[row(m)] @ B[n]^T + bias; M=4096 (b*32+i), N=2048.
// fwd row = b*T+s ; bwd row = b*T+clamp(L-1-s).

__global__ __launch_bounds__(256) void gemm_gx(
    const u16* __restrict__ A, const u16* __restrict__ Bf, const u16* __restrict__ Bb,
    const float* __restrict__ biasf, const float* __restrict__ biasb,
    u16* __restrict__ gxc, const int* __restrict__ len, int s0, int K,
    uint4* __restrict__ hseq_poison)
{
  // poison hseq for the following scan (runs after the previous scan finished;
  // kernel-end flush makes these visible to the scan's sc1 loads)
  {
    int ftid = (((blockIdx.z * gridDim.y + blockIdx.y) * gridDim.x + blockIdx.x) * 256)
               + threadIdx.x;                   // 0 .. 262143
    uint4 P; P.x = P.y = P.z = P.w = 0x7FFF7FFFu;
    hseq_poison[ftid * 2] = P;
    hseq_poison[ftid * 2 + 1] = P;              // 2 * 262144 * 16B = 8 MB
  }

  const int dir = blockIdx.z;
  const u16* Bm = dir ? Bb : Bf;
  const float* bias = dir ? biasb : biasf;
  u16* Cp = gxc + (size_t)dir * 4096 * 2048;
  __shared__ u16 As[128 * 40];
  __shared__ u16 Bs[128 * 40];
  const int tid = threadIdx.x;
  const int lane = tid & 63;
  const int wv = tid >> 6;
  const int wr = (wv >> 1) * 64, wc = (wv & 1) * 64;
  const int m16 = lane & 15, quad = lane >> 4;
  const int rowst = tid >> 1;
  const int offst = (tid & 1) * 16;
  const int m0 = blockIdx.x * 128;
  const int n0 = blockIdx.y * 128;

  const int m = m0 + rowst;
  const int b = m >> 5, i = m & 31, s = s0 + i;
  int pos;
  if (dir) { int p = len[b] - 1 - s; pos = p < 0 ? 0 : p; } else { pos = s; }
  const u16* Arow = A + ((size_t)b * TT + pos) * K;
  const u16* Brow = Bm + (size_t)(n0 + rowst) * K;

  f32x4 acc[4][4];
#pragma unroll
  for (int a = 0; a < 4; ++a)
#pragma unroll
    for (int c = 0; c < 4; ++c) acc[a][c] = zf4();

  for (int kt = 0; kt < K; kt += 32) {
    *(uint4*)&As[rowst * 40 + offst]     = *(const uint4*)(Arow + kt + offst);
    *(uint4*)&As[rowst * 40 + offst + 8] = *(const uint4*)(Arow + kt + offst + 8);
    *(uint4*)&Bs[rowst * 40 + offst]     = *(const uint4*)(Brow + kt + offst);
    *(uint4*)&Bs[rowst * 40 + offst + 8] = *(const uint4*)(Brow + kt + offst + 8);
    __syncthreads();
    f16x8 af[4], bfr[4];
#pragma unroll
    for (int mt = 0; mt < 4; ++mt)
      af[mt] = *(const f16x8*)&As[(wr + mt * 16 + m16) * 40 + quad * 8];
#pragma unroll
    for (int nt = 0; nt < 4; ++nt)
      bfr[nt] = *(const f16x8*)&Bs[(wc + nt * 16 + m16) * 40 + quad * 8];
#pragma unroll
    for (int mt = 0; mt < 4; ++mt)
#pragma unroll
      for (int nt = 0; nt < 4; ++nt)
        acc[mt][nt] = __builtin_amdgcn_mfma_f32_16x16x32_f16(af[mt], bfr[nt], acc[mt][nt], 0, 0, 0);
    __syncthreads();
  }

#pragma unroll
  for (int mt = 0; mt < 4; ++mt)
#pragma unroll
    for (int nt = 0; nt < 4; ++nt) {
      const int n = n0 + wc + nt * 16 + m16;
      const float bv = bias[n];
#pragma unroll
      for (int r = 0; r < 4; ++r) {
        const int mm = m0 + wr + mt * 16 + quad * 4 + r;
        Cp[(size_t)mm * 2048 + n] = f2h(acc[mt][nt][r] + bv);
      }
    }
}

// ---------------- classifier partial GEMM (K=512 half), accumulate into d_out

__global__ __launch_bounds__(256) void gemm_cls(
    const u16* __restrict__ out2c, const u16* __restrict__ wcls,
    float* __restrict__ dout, const int* __restrict__ len, int s0)
{
  const int dir = blockIdx.z;
  __shared__ u16 As[128 * 40];
  __shared__ u16 Bs[128 * 40];
  const int tid = threadIdx.x;
  const int lane = tid & 63;
  const int wv = tid >> 6;
  const int wr = (wv >> 1) * 64, wc = (wv & 1) * 64;
  const int m16 = lane & 15, quad = lane >> 4;
  const int rowst = tid >> 1;
  const int offst = (tid & 1) * 16;
  const int m0 = blockIdx.x * 128;
  const u16* Arow = out2c + (size_t)(m0 + rowst) * 1024 + dir * 512;
  const int rowb = rowst < 64 ? rowst : 63;
  const u16* Brow = wcls + (size_t)rowb * 1024 + dir * 512;

  f32x4 acc[4][4];
#pragma unroll
  for (int a = 0; a < 4; ++a)
#pragma unroll
    for (int c = 0; c < 4; ++c) acc[a][c] = zf4();

  for (int kt = 0; kt < 512; kt += 32) {
    *(uint4*)&As[rowst * 40 + offst]     = *(const uint4*)(Arow + kt + offst);
    *(uint4*)&As[rowst * 40 + offst + 8] = *(const uint4*)(Arow + kt + offst + 8);
    *(uint4*)&Bs[rowst * 40 + offst]     = *(const uint4*)(Brow + kt + offst);
    *(uint4*)&Bs[rowst * 40 + offst + 8] = *(const uint4*)(Brow + kt + offst + 8);
    __syncthreads();
    f16x8 af[4], bfr[4];
#pragma unroll
    for (int mt = 0; mt < 4; ++mt)
      af[mt] = *(const f16x8*)&As[(wr + mt * 16 + m16) * 40 + quad * 8];
#pragma unroll
    for (int nt = 0; nt < 4; ++nt)
      bfr[nt] = *(const f16x8*)&Bs[(wc + nt * 16 + m16) * 40 + quad * 8];
#pragma unroll
    for (int mt = 0; mt < 4; ++mt)
#pragma unroll
      for (int nt = 0; nt < 4; ++nt)
        acc[mt][nt] = __builtin_amdgcn_mfma_f32_16x16x32_f16(af[mt], bfr[nt], acc[mt][nt], 0, 0, 0);
    __syncthreads();
  }

#pragma unroll
  for (int mt = 0; mt < 4; ++mt)
#pragma unroll
    for (int nt = 0; nt < 4; ++nt) {
      const int n = wc + nt * 16 + m16;
      if (n < 64) {
#pragma unroll
        for (int r = 0; r < 4; ++r) {
          const int m = m0 + wr + mt * 16 + quad * 4 + r;
          const int b = m >> 5, i = m & 31, s = s0 + i;
          const int L = len[b];
          if (s < L) {
            const int pos = dir ? (L - 1 - s) : s;
            atomicAdd(&dout[((size_t)b * TT + pos) * 64 + n], acc[mt][nt][r]);
          }
        }
      }
    }
}

// ---------------- launch ----------------

extern "C" void kernel_launch(void* const* d_in, const int* in_sizes, int n_in,
                              void* d_out, int out_size, void* d_ws, size_t ws_size,
                              hipStream_t stream) {
  const int*   x      = (const int*)d_in[0];
  const int*   len    = (const int*)d_in[1];
  const float* emb    = (const float*)d_in[2];
  const float* Wih_f1 = (const float*)d_in[3];
  const float* Whh_f1 = (const float*)d_in[4];
  const float* b_f1   = (const float*)d_in[5];
  const float* Wih_b1 = (const float*)d_in[6];
  const float* Whh_b1 = (const float*)d_in[7];
  const float* b_b1   = (const float*)d_in[8];
  const float* Wih_f2 = (const float*)d_in[9];
  const float* Whh_f2 = (const float*)d_in[10];
  const float* b_f2   = (const float*)d_in[11];
  const float* Wih_b2 = (const float*)d_in[12];
  const float* Whh_b2 = (const float*)d_in[13];
  const float* b_b2   = (const float*)d_in[14];
  const float* W_cls  = (const float*)d_in[15];
  const float* b_cls  = (const float*)d_in[16];

  const size_t GXC  = (size_t)2 * 4096 * 2048 * 2;     // 32 MB
  const size_t OUT1 = (size_t)65536 * 1024 * 2;        // 128 MB
  const size_t EREG = (size_t)65536 * 256 * 2;         // 32 MB (also out2 chunk 8 MB)
  const size_t WTS  = (size_t)9502720 * 2;             // 18.1 MB
  const size_t HSEQ = (size_t)2 * CH * 128 * 512 * 2;  // 8 MB
  const size_t HCAR = (size_t)2 * 128 * 512 * 2;       // 256 KB
  const size_t NEED = GXC + OUT1 + EREG + WTS + HSEQ + HCAR + 524288;
  if (ws_size < NEED) {
    fill_diag<<<dim3((out_size + 255) / 256), dim3(256), 0, stream>>>(
        (float*)d_out, out_size, (float)(ws_size >> 20));
    return;
  }

  char* w = (char*)d_ws;
  u16* gxc   = (u16*)w; w += GXC;
  u16* out1  = (u16*)w; w += OUT1;
  u16* ereg  = (u16*)w; w += EREG;     // e (layer1) -> out2 chunk (layer2)
  u16* wihf1 = (u16*)w; w += (size_t)2048 * 256 * 2;
  u16* wihb1 = (u16*)w; w += (size_t)2048 * 256 * 2;
  u16* whhf1 = (u16*)w; w += (size_t)2048 * 512 * 2;
  u16* whhb1 = (u16*)w; w += (size_t)2048 * 512 * 2;
  u16* wihf2 = (u16*)w; w += (size_t)2048 * 1024 * 2;
  u16* wihb2 = (u16*)w; w += (size_t)2048 * 1024 * 2;
  u16* whhf2 = (u16*)w; w += (size_t)2048 * 512 * 2;
  u16* whhb2 = (u16*)w; w += (size_t)2048 * 512 * 2;
  u16* wcls  = (u16*)w; w += (size_t)64 * 1024 * 2;
  u16* hseq  = (u16*)w; w += HSEQ;
  u16* hcarry = (u16*)w; w += HCAR;
  float* cbuf = (float*)w; w += 524288;

  u16* e     = ereg;
  u16* out2c = ereg;   // 8 MB, live only in layer 2

  CvtJobs jobs = {{
    { Wih_f1, wihf1, 2048 * 256 }, { Wih_b1, wihb1, 2048 * 256 },
    { Whh_f1, whhf1, 2048 * 512 }, { Whh_b1, whhb1, 2048 * 512 },
    { Wih_f2, wihf2, 2048 * 1024 }, { Wih_b2, wihb2, 2048 * 1024 },
    { Whh_f2, whhf2, 2048 * 512 }, { Whh_b2, whhb2, 2048 * 512 },
    { W_cls,  wcls,  64 * 1024 },
  }};
  cvt_many<<<dim3(8192, 9), dim3(256), 0, stream>>>(jobs);
  embed_cast<<<dim3(65536), dim3(256), 0, stream>>>(x, emb, e);
  bias_init<<<dim3(16384), dim3(256), 0, stream>>>((float*)d_out, b_cls, 65536 * 64);

  // layer 1
  for (int c = 0; c < NCH; ++c) {
    gemm_gx<<<dim3(32, 16, 2), dim3(256), 0, stream>>>(
        e, wihf1, wihb1, b_f1, b_b1, gxc, len, c * CH, 256, (uint4*)hseq);
    lstm_scan<<<dim3(256), dim3(128), 0, stream>>>(
        gxc, whhf1, whhb1, len, out1, nullptr, hseq, hcarry, cbuf, c * CH);
  }
  // layer 2 + chunked classifier
  for (int c = 0; c < NCH; ++c) {
    gemm_gx<<<dim3(32, 16, 2), dim3(256), 0, stream>>>(
        out1, wihf2, wihb2, b_f2, b_b2, gxc, len, c * CH, 1024, (uint4*)hseq);
    lstm_scan<<<dim3(256), dim3(128), 0, stream>>>(
        gxc, whhf2, whhb2, len, nullptr, out2c, hseq, hcarry, cbuf, c * CH);
    gemm_cls<<<dim3(32, 1, 2), dim3(256), 0, stream>>>(
        out2c, wcls, (float*)d_out, len, c * CH);
  }
}

// Round 10
// 6658.736 us; speedup vs baseline: 1.2227x; 1.2227x over previous
//
#include <hip/hip_runtime.h>

// BiLSTMTagger on MI355X (gfx950) — 256 MB workspace budget.
// Chunked pipeline (16 chunks x 32 steps per layer):
//   gemm_gx(chunk): gathered-A GEMM -> gx chunk (bwd pre-gathered).
//   lstm_scan(chunk): persistent 256-block scan, W_hh register/AGPR-resident.
//     Sync: XCD-LOCALITY AS AN OPTIMIZATION, NEVER AN ASSUMPTION.
//     - Groups are formed statically from the round-robin dispatch guess:
//       blocks with equal blockIdx&7 share one XCD (if the guess is right).
//     - Producers DUAL-STORE h granules and tags: sc0 (own XCD L2) + sc1
//       (LLC). One vmcnt(0) orders h (both scopes) before tags (both scopes).
//     - h slots are per-step (hseq, write-once within a dispatch) so consumer
//       sc0 h loads are always first-touch: dirty-L2 hit when co-located,
//       LLC fill otherwise — correct either way.
//     - Tag polls alternate sc0/sc1 iterations: co-located tags advance in L2
//       (~200cyc), remote tags are seen via LLC. No watchdog, no deadlock.
//   layer2: scan emits step-indexed chunk buffer; classifier = two separable
//           K=512 partial GEMMs accumulating into bias-initialized d_out.
// fp16 storage/MFMA, fp32 cell math.

typedef unsigned short u16;
typedef unsigned long long u64;
typedef _Float16 f16;
typedef __attribute__((ext_vector_type(8))) _Float16 f16x8;
typedef __attribute__((ext_vector_type(4))) float f32x4;

#define TT 512
#define HH 512
#define CH 32          // steps per chunk
#define NCH 16         // chunks
#define TSTR 16        // tag stride in ints: 64B line per tag

__device__ __forceinline__ u16 f2h(float f) { f16 h = (f16)f; return __builtin_bit_cast(u16, h); }
__device__ __forceinline__ float h2f(u16 s) { return (float)__builtin_bit_cast(f16, s); }
__device__ __forceinline__ float sigf(float x) { return 1.f / (1.f + __expf(-x)); }
__device__ __forceinline__ float tanhf_(float x) { return 1.f - 2.f / (__expf(2.f * x) + 1.f); }
__device__ __forceinline__ f32x4 zf4() { f32x4 z; z[0]=0.f; z[1]=0.f; z[2]=0.f; z[3]=0.f; return z; }

// sc0: bypass L1, coherent within this XCD's L2. sc1: bypass L2, LLC-coherent.
__device__ __forceinline__ void st16_sc0(u16* p, f16x8 v) {
  asm volatile("global_store_dwordx4 %0, %1, off sc0" :: "v"(p), "v"(v) : "memory");
}
__device__ __forceinline__ void st16_sc1(u16* p, f16x8 v) {
  asm volatile("global_store_dwordx4 %0, %1, off sc1" :: "v"(p), "v"(v) : "memory");
}
__device__ __forceinline__ f16x8 ld16_sc0(const u16* p) {
  f16x8 v;
  asm volatile("global_load_dwordx4 %0, %1, off sc0" : "=v"(v) : "v"(p) : "memory");
  return v;
}
__device__ __forceinline__ void sttag_sc0(int* p, int v) {
  asm volatile("global_store_dword %0, %1, off sc0" :: "v"(p), "v"(v) : "memory");
}
__device__ __forceinline__ void sttag_sc1(int* p, int v) {
  asm volatile("global_store_dword %0, %1, off sc1" :: "v"(p), "v"(v) : "memory");
}
__device__ __forceinline__ int ldtag_sc0(const int* p) {
  int v;
  asm volatile("global_load_dword %0, %1, off sc0" : "=v"(v) : "v"(p) : "memory");
  return v;
}
__device__ __forceinline__ int ldtag_sc1(const int* p) {
  int v;
  asm volatile("global_load_dword %0, %1, off sc1" : "=v"(v) : "v"(p) : "memory");
  return v;
}

// ---------------- utility kernels ----------------

struct CvtJob { const float* s; u16* d; int n; };
struct CvtJobs { CvtJob j[9]; };

__global__ void cvt_many(CvtJobs jobs) {
  CvtJob jb = jobs.j[blockIdx.y];
  int i = blockIdx.x * 256 + threadIdx.x;
  if (i < jb.n) jb.d[i] = f2h(jb.s[i]);
}

__global__ void embed_cast(const int* __restrict__ x, const float* __restrict__ emb,
                           u16* __restrict__ e) {
  int row = blockIdx.x;
  int tok = x[row];
  e[(size_t)row * 256 + threadIdx.x] = f2h(emb[(size_t)tok * 256 + threadIdx.x]);
}

__global__ void bias_init(float* __restrict__ o, const float* __restrict__ b, int n) {
  int i = blockIdx.x * 256 + threadIdx.x;
  if (i < n) o[i] = b[i & 63];
}

__global__ void fill_diag(float* __restrict__ o, int n, float sentinel) {
  int i = blockIdx.x * 256 + threadIdx.x;
  if (i < n) o[i] = (i == 0) ? sentinel : 0.f;
}

// ---------------- persistent BiLSTM scan, one chunk ----------------
// grid 256 x 128 thr (2 waves/block). Static grouping from the round-robin
// dispatch guess: bg = blockIdx&7 (XCD residue), rank = blockIdx>>3,
// dir = rank>>4, role = rank&15. Group = 16 blocks of one residue half.
// hseq[(dir*CH+slot)][128][512]: h after step s0+slot, one slot per step.
// tags[(grp*32+u_tile)*TSTR]: monotone, tagbase+i+1 after slot i published.

__global__ __launch_bounds__(128, 1) void lstm_scan(
    const u16* __restrict__ gxc, const u16* __restrict__ whh_f,
    const u16* __restrict__ whh_b, const int* __restrict__ len,
    u16* __restrict__ out_pos, u16* __restrict__ out_chunk,
    u16* __restrict__ hseq, u16* __restrict__ hcarry,
    float* __restrict__ cbuf, int* __restrict__ tags,
    int s0, int tagbase)
{
  __shared__ u16 tb[2][256];                 // 16x16 transpose tile per wave
  const int tid = threadIdx.x;
  const int bi = blockIdx.x;
  const int bg = bi & 7;                     // batch-group == XCD residue guess
  const int rank = bi >> 3;                  // 0..31 within residue
  const int dir = rank >> 4;
  const int role = rank & 15;
  const int b_base = bg * 16;
  const int grp = dir * 8 + bg;
  const int u_tile = role * 2 + (tid >> 6);  // 0..31 within group
  const int u_base = u_tile * 16;
  const int lane = tid & 63;
  const int m16 = lane & 15, quad = lane >> 4;
  const u16* gxd = gxc + (size_t)dir * 4096 * 2048;
  const u16* whh = dir ? whh_b : whh_f;
  u16* T = tb[tid >> 6];
  int* gtags = tags + grp * 32 * TSTR;
  int* mytag = gtags + u_tile * TSTR;

  // W_hh fragments: B[n=lane&15][k=quad*8+j] — 256 regs, AGPR-resident.
  f16x8 bf[4][16];
#pragma unroll
  for (int g = 0; g < 4; ++g) {
    const u16* wrow = whh + (size_t)(g * HH + u_base + m16) * HH + quad * 8;
#pragma unroll
    for (int ks = 0; ks < 16; ++ks)
      bf[g][ks] = *(const f16x8*)(wrow + ks * 32);
  }

  int lenr[4];
#pragma unroll
  for (int r = 0; r < 4; ++r) lenr[r] = len[b_base + quad * 4 + r];

  float cst[4];
  if (s0 == 0) {
#pragma unroll
    for (int r = 0; r < 4; ++r) cst[r] = 0.f;
  } else {
#pragma unroll
    for (int r = 0; r < 4; ++r)
      cst[r] = cbuf[(size_t)dir * 65536 + (b_base + quad * 4 + r) * HH + u_base + m16];
  }

  const u16* carry_rd = hcarry + (size_t)dir * 65536 + (b_base + m16) * HH + quad * 8;

  for (int i = 0; i < CH; ++i) {
    const int s = s0 + i;

    // gx prefetch (plain loads; drained by the first poll iteration)
    u16 gpre[4][4];
#pragma unroll
    for (int r = 0; r < 4; ++r) {
      const int batch = b_base + quad * 4 + r;
      const u16* gq = gxd + (size_t)(batch * CH + i) * 2048 + u_base + m16;
      gpre[r][0] = gq[0]; gpre[r][1] = gq[512];
      gpre[r][2] = gq[1024]; gpre[r][3] = gq[1536];
    }

    // A fragments = h[s-1]
    f16x8 a[16];
    if (i == 0) {
      if (s0 == 0) {
#pragma unroll
        for (int ks = 0; ks < 16; ++ks)
#pragma unroll
          for (int j = 0; j < 8; ++j) a[ks][j] = (f16)0.f;
      } else {
#pragma unroll
        for (int ks = 0; ks < 16; ++ks)
          a[ks] = *(const f16x8*)(carry_rd + ks * 32);   // kernel-boundary coherent
      }
    } else {
      // tag poll: alternate sc0 (fast when co-located; may be a stuck cached
      // line when not) and sc1 (always-fresh LLC). Progress guaranteed by the
      // sc1 iterations; speed provided by the sc0 ones.
      const int want = tagbase + i;
      const int* myp = gtags + (lane & 31) * TSTR;
      int it = 0;
      while (true) {
        int t = (it & 1) ? ldtag_sc1(myp) : ldtag_sc0(myp);
        asm volatile("s_waitcnt vmcnt(0)" ::: "memory");
        if (__ballot(t < want) == 0ull) break;
        ++it;
        __builtin_amdgcn_s_sleep(1);
      }
      // h loads sc0: slot addresses are first-touch this dispatch, so this is
      // either a dirty-L2 hit (co-located producer) or an LLC fill (dual-store
      // guarantees LLC is current) — correct under ANY block->XCD mapping.
      const u16* sb = hseq + ((size_t)(dir * CH + (i - 1)) * 128 + b_base + m16) * HH + quad * 8;
#pragma unroll
      for (int ks = 0; ks < 16; ++ks) a[ks] = ld16_sc0(sb + ks * 32);
      asm volatile("s_waitcnt vmcnt(0)" ::: "memory");
    }

    f32x4 a0 = zf4(), a1 = zf4(), a2 = zf4(), a3 = zf4();
#pragma unroll
    for (int ks = 0; ks < 16; ++ks) {
      a0 = __builtin_amdgcn_mfma_f32_16x16x32_f16(a[ks], bf[0][ks], a0, 0, 0, 0);
      a1 = __builtin_amdgcn_mfma_f32_16x16x32_f16(a[ks], bf[1][ks], a1, 0, 0, 0);
      a2 = __builtin_amdgcn_mfma_f32_16x16x32_f16(a[ks], bf[2][ks], a2, 0, 0, 0);
      a3 = __builtin_amdgcn_mfma_f32_16x16x32_f16(a[ks], bf[3][ks], a3, 0, 0, 0);
    }

    // cell math
    u16 hv[4];
#pragma unroll
    for (int r = 0; r < 4; ++r) {
      float gi = a0[r] + h2f(gpre[r][0]);
      float gf = a1[r] + h2f(gpre[r][1]);
      float gg = a2[r] + h2f(gpre[r][2]);
      float go = a3[r] + h2f(gpre[r][3]);
      float c = sigf(gf) * cst[r] + sigf(gi) * tanhf_(gg);
      cst[r] = c;
      hv[r] = f2h(sigf(go) * tanhf_(c));
    }

    // publish h: LDS 16x16 transpose -> dual-scope granule stores -> tags
#pragma unroll
    for (int r = 0; r < 4; ++r)
      T[(quad * 4 + r) * 16 + m16] = hv[r];
    if (lane < 32) {
      const int brow = lane >> 1, col8 = (lane & 1) * 8;
      f16x8 hrow = *(const f16x8*)&T[brow * 16 + col8];
      if (i == CH - 1) {
        *(f16x8*)(hcarry + (size_t)dir * 65536 + (b_base + brow) * HH + u_base + col8) = hrow;
      } else {
        u16* dst = hseq + ((size_t)(dir * CH + i) * 128 + b_base + brow) * HH + u_base + col8;
        st16_sc0(dst, hrow);
        st16_sc1(dst, hrow);
      }
    }
    if (i != CH - 1) {
      asm volatile("s_waitcnt vmcnt(0)" ::: "memory");   // h at L2 AND LLC
      if (lane == 0) { sttag_sc0(mytag, tagbase + i + 1); sttag_sc1(mytag, tagbase + i + 1); }
    }

    // outputs (plain stores, off the publish path)
#pragma unroll
    for (int r = 0; r < 4; ++r) {
      const int batch = b_base + quad * 4 + r;
      const int L = lenr[r];
      const bool valid = s < L;
      if (out_pos) {
        const int p = dir ? (L - 1 - s) : s;
        const int wrow = valid ? (p < 0 ? 0 : p) : s;
        out_pos[(size_t)(batch * TT + wrow) * 1024 + dir * 512 + u_base + m16]
            = valid ? hv[r] : (u16)0;
      } else {
        out_chunk[(size_t)(batch * CH + i) * 1024 + dir * 512 + u_base + m16] = hv[r];
      }
    }
  }

#pragma unroll
  for (int r = 0; r < 4; ++r)
    cbuf[(size_t)dir * 65536 + (b_base + quad * 4 + r) * HH + u_base + m16] = cst[r];
}

// ---------------- gx GEMM (gathered A rows) ----------------
// gxc[dir][m][n] = A[row(m)] @ B[n]^T + bias; M=4096 (b*32+i), N=2048.

__global__ __launch_bounds__(256) void gemm_gx(
    const u16* __restrict__ A, const u16* __restrict__ Bf, const u16* __restrict__ Bb,
    const float* __restrict__ biasf, const float* __restrict__ biasb,
    u16* __restrict__ gxc, const int* __restrict__ len, int s0, int K)
{
  const int dir = blockIdx.z;
  const u16* Bm = dir ? Bb : Bf;
  const float* bias = dir ? biasb : biasf;
  u16* Cp = gxc + (size_t)dir * 4096 * 2048;
  __shared__ u16 As[128 * 40];
  __shared__ u16 Bs[128 * 40];
  const int tid = threadIdx.x;
  const int lane = tid & 63;
  const int wv = tid >> 6;
  const int wr = (wv >> 1) * 64, wc = (wv & 1) * 64;
  const int m16 = lane & 15, quad = lane >> 4;
  const int rowst = tid >> 1;
  const int offst = (tid & 1) * 16;
  const int m0 = blockIdx.x * 128;
  const int n0 = blockIdx.y * 128;

  const int m = m0 + rowst;
  const int b = m >> 5, i = m & 31, s = s0 + i;
  int pos;
  if (dir) { int p = len[b] - 1 - s; pos = p < 0 ? 0 : p; } else { pos = s; }
  const u16* Arow = A + ((size_t)b * TT + pos) * K;
  const u16* Brow = Bm + (size_t)(n0 + rowst) * K;

  f32x4 acc[4][4];
#pragma unroll
  for (int a = 0; a < 4; ++a)
#pragma unroll
    for (int c = 0; c < 4; ++c) acc[a][c] = zf4();

  for (int kt = 0; kt < K; kt += 32) {
    *(uint4*)&As[rowst * 40 + offst]     = *(const uint4*)(Arow + kt + offst);
    *(uint4*)&As[rowst * 40 + offst + 8] = *(const uint4*)(Arow + kt + offst + 8);
    *(uint4*)&Bs[rowst * 40 + offst]     = *(const uint4*)(Brow + kt + offst);
    *(uint4*)&Bs[rowst * 40 + offst + 8] = *(const uint4*)(Brow + kt + offst + 8);
    __syncthreads();
    f16x8 af[4], bfr[4];
#pragma unroll
    for (int mt = 0; mt < 4; ++mt)
      af[mt] = *(const f16x8*)&As[(wr + mt * 16 + m16) * 40 + quad * 8];
#pragma unroll
    for (int nt = 0; nt < 4; ++nt)
      bfr[nt] = *(const f16x8*)&Bs[(wc + nt * 16 + m16) * 40 + quad * 8];
#pragma unroll
    for (int mt = 0; mt < 4; ++mt)
#pragma unroll
      for (int nt = 0; nt < 4; ++nt)
        acc[mt][nt] = __builtin_amdgcn_mfma_f32_16x16x32_f16(af[mt], bfr[nt], acc[mt][nt], 0, 0, 0);
    __syncthreads();
  }

#pragma unroll
  for (int mt = 0; mt < 4; ++mt)
#pragma unroll
    for (int nt = 0; nt < 4; ++nt) {
      const int n = n0 + wc + nt * 16 + m16;
      const float bv = bias[n];
#pragma unroll
      for (int r = 0; r < 4; ++r) {
        const int mm = m0 + wr + mt * 16 + quad * 4 + r;
        Cp[(size_t)mm * 2048 + n] = f2h(acc[mt][nt][r] + bv);
      }
    }
}

// ---------------- classifier partial GEMM (K=512 half), accumulate into d_out

__global__ __launch_bounds__(256) void gemm_cls(
    const u16* __restrict__ out2c, const u16* __restrict__ wcls,
    float* __restrict__ dout, const int* __restrict__ len, int s0)
{
  const int dir = blockIdx.z;
  __shared__ u16 As[128 * 40];
  __shared__ u16 Bs[128 * 40];
  const int tid = threadIdx.x;
  const int lane = tid & 63;
  const int wv = tid >> 6;
  const int wr = (wv >> 1) * 64, wc = (wv & 1) * 64;
  const int m16 = lane & 15, quad = lane >> 4;
  const int rowst = tid >> 1;
  const int offst = (tid & 1) * 16;
  const int m0 = blockIdx.x * 128;
  const u16* Arow = out2c + (size_t)(m0 + rowst) * 1024 + dir * 512;
  const int rowb = rowst < 64 ? rowst : 63;
  const u16* Brow = wcls + (size_t)rowb * 1024 + dir * 512;

  f32x4 acc[4][4];
#pragma unroll
  for (int a = 0; a < 4; ++a)
#pragma unroll
    for (int c = 0; c < 4; ++c) acc[a][c] = zf4();

  for (int kt = 0; kt < 512; kt += 32) {
    *(uint4*)&As[rowst * 40 + offst]     = *(const uint4*)(Arow + kt + offst);
    *(uint4*)&As[rowst * 40 + offst + 8] = *(const uint4*)(Arow + kt + offst + 8);
    *(uint4*)&Bs[rowst * 40 + offst]     = *(const uint4*)(Brow + kt + offst);
    *(uint4*)&Bs[rowst * 40 + offst + 8] = *(const uint4*)(Brow + kt + offst + 8);
    __syncthreads();
    f16x8 af[4], bfr[4];
#pragma unroll
    for (int mt = 0; mt < 4; ++mt)
      af[mt] = *(const f16x8*)&As[(wr + mt * 16 + m16) * 40 + quad * 8];
#pragma unroll
    for (int nt = 0; nt < 4; ++nt)
      bfr[nt] = *(const f16x8*)&Bs[(wc + nt * 16 + m16) * 40 + quad * 8];
#pragma unroll
    for (int mt = 0; mt < 4; ++mt)
#pragma unroll
      for (int nt = 0; nt < 4; ++nt)
        acc[mt][nt] = __builtin_amdgcn_mfma_f32_16x16x32_f16(af[mt], bfr[nt], acc[mt][nt], 0, 0, 0);
    __syncthreads();
  }

#pragma unroll
  for (int mt = 0; mt < 4; ++mt)
#pragma unroll
    for (int nt = 0; nt < 4; ++nt) {
      const int n = wc + nt * 16 + m16;
      if (n < 64) {
#pragma unroll
        for (int r = 0; r < 4; ++r) {
          const int m = m0 + wr + mt * 16 + quad * 4 + r;
          const int b = m >> 5, i = m & 31, s = s0 + i;
          const int L = len[b];
          if (s < L) {
            const int pos = dir ? (L - 1 - s) : s;
            atomicAdd(&dout[((size_t)b * TT + pos) * 64 + n], acc[mt][nt][r]);
          }
        }
      }
    }
}

// ---------------- launch ----------------

extern "C" void kernel_launch(void* const* d_in, const int* in_sizes, int n_in,
                              void* d_out, int out_size, void* d_ws, size_t ws_size,
                              hipStream_t stream) {
  const int*   x      = (const int*)d_in[0];
  const int*   len    = (const int*)d_in[1];
  const float* emb    = (const float*)d_in[2];
  const float* Wih_f1 = (const float*)d_in[3];
  const float* Whh_f1 = (const float*)d_in[4];
  const float* b_f1   = (const float*)d_in[5];
  const float* Wih_b1 = (const float*)d_in[6];
  const float* Whh_b1 = (const float*)d_in[7];
  const float* b_b1   = (const float*)d_in[8];
  const float* Wih_f2 = (const float*)d_in[9];
  const float* Whh_f2 = (const float*)d_in[10];
  const float* b_f2   = (const float*)d_in[11];
  const float* Wih_b2 = (const float*)d_in[12];
  const float* Whh_b2 = (const float*)d_in[13];
  const float* b_b2   = (const float*)d_in[14];
  const float* W_cls  = (const float*)d_in[15];
  const float* b_cls  = (const float*)d_in[16];

  const size_t GXC  = (size_t)2 * 4096 * 2048 * 2;     // 32 MB
  const size_t OUT1 = (size_t)65536 * 1024 * 2;        // 128 MB
  const size_t EREG = (size_t)65536 * 256 * 2;         // 32 MB (also out2 chunk 8 MB)
  const size_t WTS  = (size_t)9502720 * 2;             // 18.1 MB
  const size_t HSEQ = (size_t)2 * CH * 128 * 512 * 2;  // 8 MB
  const size_t HCAR = (size_t)2 * 128 * 512 * 2;       // 256 KB
  const size_t TAGS = 16 * 32 * TSTR * 4;              // 32 KB
  const size_t NEED = GXC + OUT1 + EREG + WTS + HSEQ + HCAR + 524288 + TAGS;
  if (ws_size < NEED) {
    fill_diag<<<dim3((out_size + 255) / 256), dim3(256), 0, stream>>>(
        (float*)d_out, out_size, (float)(ws_size >> 20));
    return;
  }

  char* w = (char*)d_ws;
  u16* gxc   = (u16*)w; w += GXC;
  u16* out1  = (u16*)w; w += OUT1;
  u16* ereg  = (u16*)w; w += EREG;     // e (layer1) -> out2 chunk (layer2)
  u16* wihf1 = (u16*)w; w += (size_t)2048 * 256 * 2;
  u16* wihb1 = (u16*)w; w += (size_t)2048 * 256 * 2;
  u16* whhf1 = (u16*)w; w += (size_t)2048 * 512 * 2;
  u16* whhb1 = (u16*)w; w += (size_t)2048 * 512 * 2;
  u16* wihf2 = (u16*)w; w += (size_t)2048 * 1024 * 2;
  u16* wihb2 = (u16*)w; w += (size_t)2048 * 1024 * 2;
  u16* whhf2 = (u16*)w; w += (size_t)2048 * 512 * 2;
  u16* whhb2 = (u16*)w; w += (size_t)2048 * 512 * 2;
  u16* wcls  = (u16*)w; w += (size_t)64 * 1024 * 2;
  u16* hseq  = (u16*)w; w += HSEQ;
  u16* hcarry = (u16*)w; w += HCAR;
  float* cbuf = (float*)w; w += 524288;
  int* tags  = (int*)w; w += TAGS;

  u16* e     = ereg;
  u16* out2c = ereg;   // 8 MB, live only in layer 2

  CvtJobs jobs = {{
    { Wih_f1, wihf1, 2048 * 256 }, { Wih_b1, wihb1, 2048 * 256 },
    { Whh_f1, whhf1, 2048 * 512 }, { Whh_b1, whhb1, 2048 * 512 },
    { Wih_f2, wihf2, 2048 * 1024 }, { Wih_b2, wihb2, 2048 * 1024 },
    { Whh_f2, whhf2, 2048 * 512 }, { Whh_b2, whhb2, 2048 * 512 },
    { W_cls,  wcls,  64 * 1024 },
  }};
  cvt_many<<<dim3(8192, 9), dim3(256), 0, stream>>>(jobs);
  embed_cast<<<dim3(65536), dim3(256), 0, stream>>>(x, emb, e);
  bias_init<<<dim3(16384), dim3(256), 0, stream>>>((float*)d_out, b_cls, 65536 * 64);
  hipMemsetAsync(tags, 0, TAGS, stream);    // tags monotone within one launch

  int seq = 0;
  // layer 1
  for (int c = 0; c < NCH; ++c) {
    gemm_gx<<<dim3(32, 16, 2), dim3(256), 0, stream>>>(
        e, wihf1, wihb1, b_f1, b_b1, gxc, len, c * CH, 256);
    lstm_scan<<<dim3(256), dim3(128), 0, stream>>>(
        gxc, whhf1, whhb1, len, out1, nullptr, hseq, hcarry, cbuf, tags,
        c * CH, seq * CH);
    ++seq;
  }
  // layer 2 + chunked classifier
  for (int c = 0; c < NCH; ++c) {
    gemm_gx<<<dim3(32, 16, 2), dim3(256), 0, stream>>>(
        out1, wihf2, wihb2, b_f2, b_b2, gxc, len, c * CH, 1024);
    lstm_scan<<<dim3(256), dim3(128), 0, stream>>>(
        gxc, whhf2, whhb2, len, nullptr, out2c, hseq, hcarry, cbuf, tags,
        c * CH, seq * CH);
    ++seq;
    gemm_cls<<<dim3(32, 1, 2), dim3(256), 0, stream>>>(
        out2c, wcls, (float*)d_out, len, c * CH);
  }
}